// Round 1
// baseline (120963.123 us; speedup 1.0000x reference)
//
#include <hip/hip_runtime.h>
#include <hip/hip_bf16.h>

// HRM-LM on MI355X.
// Strategy: persistent cooperative kernel (128 WGs, 1/CU) runs the serial
// recurrence with low_Wh resident in LDS; device-wide sync via per-round
// counters in ws (zeroed by hipMemsetAsync each launch -> graph-safe,
// deterministic). h_h history logged as bf16; logits done by one deferred
// bf16 MFMA GEMM [2048,768]x[768,32000].

#define NWG 128
#define NTH 256
#define EPSV 1e-5f
#define NROUND 4608   // 256 * 3 * (5 inner + 1 high)

typedef __attribute__((ext_vector_type(4))) float f32x4;
typedef __attribute__((ext_vector_type(8))) short short8;

struct PArgs {
  const int* ids; const float* emb; const float* lng; const float* lnb;
  const float* lWi; const float* lbi; const float* lWh; const float* lbh;
  const float* llig; const float* llib; const float* llhg; const float* llhb;
  const float* hWi; const float* hbi; const float* hWh; const float* hbh;
  const float* hlig; const float* hlib; const float* hlhg; const float* hlhb;
  int* cnt; float* stats; float* hl; float* hh; float* xcat;
  __hip_bfloat16* hist; float* WiT; float* hWiT; float* hWhT;
};

__device__ __forceinline__ int swz(int k) { return k ^ (((k >> 5) & 7) << 2); }
__device__ __forceinline__ float sigm(float x) { return 1.f / (1.f + __expf(-x)); }
__device__ __forceinline__ float tanh_f(float x) {
  x = fminf(15.f, fmaxf(-15.f, x));
  float e = __expf(2.f * x);
  return (e - 1.f) / (e + 1.f);
}
__device__ __forceinline__ void ast(float* p, float v) {
  __hip_atomic_store(p, v, __ATOMIC_RELAXED, __HIP_MEMORY_SCOPE_AGENT);
}

__global__ void __launch_bounds__(NTH) hrm_recur(PArgs P) {
  __shared__ float WhS[24 * 1024];   // low_Wh slice [c=g*8+jj][k], swizzled k
  __shared__ float Bb[8 * 1536];     // B-operand staging [b][k], swizzled k
  __shared__ float xiNs[24 * 8];     // normalized xi, kept across inner iters
  __shared__ float stg[2][24 * 8];   // raw (bias-added) GEMM outputs
  __shared__ float xm[8], xrs[8];
  __shared__ int okf;

  const int wg = blockIdx.x, tid = threadIdx.x;
  const int ks = tid & 31, cg = tid >> 5;
  const int lj8 = wg * 8, lj6 = wg * 6;

  // ---- device-wide barrier on a per-round monotonic counter ----
  auto wgbar = [&](int* slot) -> bool {
    __syncthreads();  // drains each thread's vmcnt before arrival
    if (tid == 0) {
      __builtin_amdgcn_fence(__ATOMIC_RELEASE, "agent");
      __hip_atomic_fetch_add(slot, 1, __ATOMIC_RELAXED, __HIP_MEMORY_SCOPE_AGENT);
      int v = 0;
      for (int lim = (1 << 21); lim > 0; --lim) {
        v = __hip_atomic_load(slot, __ATOMIC_RELAXED, __HIP_MEMORY_SCOPE_AGENT);
        if (v >= NWG) break;
        __builtin_amdgcn_s_sleep(2);
      }
      __builtin_amdgcn_fence(__ATOMIC_ACQUIRE, "agent");  // invalidate L1/L2
      okf = (v >= NWG);
    }
    __syncthreads();
    return okf != 0;
  };

  // ---- staging (normal vectorized loads; fresh after acquire-inv) ----
  auto stage_hl = [&]() {
    #pragma unroll
    for (int i = 0; i < 8; ++i) {
      float4 v = *(const float4*)&P.hl[i * 1024 + tid * 4];
      *(float4*)&Bb[i * 1536 + swz(tid * 4)] = v;
    }
  };
  auto stage_xcat = [&]() {
    #pragma unroll
    for (int i = 0; i < 12; ++i) {
      int c = i * 256 + tid; int b = c / 384; int k = (c - b * 384) * 4;
      float4 v = *(const float4*)&P.xcat[b * 1536 + k];
      *(float4*)&Bb[b * 1536 + swz(k)] = v;
    }
  };
  auto stage_hh = [&]() {
    #pragma unroll
    for (int i = 0; i < 6; ++i) {
      int c = i * 256 + tid; int b = c / 192; int k = (c - b * 192) * 4;
      float4 v = *(const float4*)&P.hh[b * 768 + k];
      *(float4*)&Bb[b * 1536 + swz(k)] = v;
    }
  };

  // ---- GEMMs: thread (cg,ks) owns 3 gate-cols (c=cg*3..+2), k-slice ks ----
  auto gemm_lowh = [&](float (&acc)[3][8]) {
    const int c0 = cg * 3;
    const float* w0p = &WhS[(c0 + 0) * 1024];
    const float* w1p = &WhS[(c0 + 1) * 1024];
    const float* w2p = &WhS[(c0 + 2) * 1024];
    #pragma unroll
    for (int i = 0; i < 32; i += 4) {
      int k = ks * 32 + i, sk = swz(k);
      float4 w0 = *(const float4*)&w0p[sk];
      float4 w1 = *(const float4*)&w1p[sk];
      float4 w2 = *(const float4*)&w2p[sk];
      #pragma unroll
      for (int b = 0; b < 8; ++b) {
        float4 h = *(const float4*)&Bb[b * 1536 + sk];
        acc[0][b] += w0.x*h.x + w0.y*h.y + w0.z*h.z + w0.w*h.w;
        acc[1][b] += w1.x*h.x + w1.y*h.y + w1.z*h.z + w1.w*h.w;
        acc[2][b] += w2.x*h.x + w2.y*h.y + w2.z*h.z + w2.w*h.w;
      }
    }
  };
  auto gemm_xi = [&](float (&acc)[3][8]) {
    const float* wp[3];
    #pragma unroll
    for (int cc = 0; cc < 3; ++cc) {
      int c = cg * 3 + cc; int g = c >> 3, jj = c & 7;
      wp[cc] = P.WiT + ((size_t)g * 1024 + lj8 + jj) * 1536;
    }
    #pragma unroll
    for (int i = 0; i < 48; i += 4) {
      int k = ks * 48 + i, sk = swz(k);
      float4 w0 = *(const float4*)&wp[0][k];
      float4 w1 = *(const float4*)&wp[1][k];
      float4 w2 = *(const float4*)&wp[2][k];
      #pragma unroll
      for (int b = 0; b < 8; ++b) {
        float4 h = *(const float4*)&Bb[b * 1536 + sk];
        acc[0][b] += w0.x*h.x + w0.y*h.y + w0.z*h.z + w0.w*h.w;
        acc[1][b] += w1.x*h.x + w1.y*h.y + w1.z*h.z + w1.w*h.w;
        acc[2][b] += w2.x*h.x + w2.y*h.y + w2.z*h.z + w2.w*h.w;
      }
    }
  };
  auto gemm_hxi = [&](float (&acc)[3][8]) {  // K=1024, 18 cols
    if (cg >= 6) return;
    const float* wp[3];
    #pragma unroll
    for (int cc = 0; cc < 3; ++cc) {
      int c = cg * 3 + cc; int g = c / 6, jj = c % 6;
      wp[cc] = P.hWiT + ((size_t)g * 768 + lj6 + jj) * 1024;
    }
    #pragma unroll
    for (int i = 0; i < 32; i += 4) {
      int k = ks * 32 + i, sk = swz(k);
      float4 w0 = *(const float4*)&wp[0][k];
      float4 w1 = *(const float4*)&wp[1][k];
      float4 w2 = *(const float4*)&wp[2][k];
      #pragma unroll
      for (int b = 0; b < 8; ++b) {
        float4 h = *(const float4*)&Bb[b * 1536 + sk];
        acc[0][b] += w0.x*h.x + w0.y*h.y + w0.z*h.z + w0.w*h.w;
        acc[1][b] += w1.x*h.x + w1.y*h.y + w1.z*h.z + w1.w*h.w;
        acc[2][b] += w2.x*h.x + w2.y*h.y + w2.z*h.z + w2.w*h.w;
      }
    }
  };
  auto gemm_hhh = [&](float (&acc)[3][8]) {  // K=768, 18 cols
    if (cg >= 6) return;
    const float* wp[3];
    #pragma unroll
    for (int cc = 0; cc < 3; ++cc) {
      int c = cg * 3 + cc; int g = c / 6, jj = c % 6;
      wp[cc] = P.hWhT + ((size_t)g * 768 + lj6 + jj) * 768;
    }
    #pragma unroll
    for (int i = 0; i < 24; i += 4) {
      int k = ks * 24 + i, sk = swz(k);
      float4 w0 = *(const float4*)&wp[0][k];
      float4 w1 = *(const float4*)&wp[1][k];
      float4 w2 = *(const float4*)&wp[2][k];
      #pragma unroll
      for (int b = 0; b < 8; ++b) {
        float4 h = *(const float4*)&Bb[b * 1536 + sk];
        acc[0][b] += w0.x*h.x + w0.y*h.y + w0.z*h.z + w0.w*h.w;
        acc[1][b] += w1.x*h.x + w1.y*h.y + w1.z*h.z + w1.w*h.w;
        acc[2][b] += w2.x*h.x + w2.y*h.y + w2.z*h.z + w2.w*h.w;
      }
    }
  };

  // k-reduce over the 32 ks-slices (intra-32-lane butterfly), leaders stage
  auto redstage = [&](float (&acc)[3][8], int set, const float* bias, int dim,
                      int perg, int jb) {
    #pragma unroll
    for (int cc = 0; cc < 3; ++cc)
      #pragma unroll
      for (int b = 0; b < 8; ++b) {
        float v = acc[cc][b];
        #pragma unroll
        for (int m = 1; m < 32; m <<= 1) v += __shfl_xor(v, m, 64);
        acc[cc][b] = v;
      }
    if ((tid & 31) == 0) {
      int cgl = tid >> 5;
      #pragma unroll
      for (int cc = 0; cc < 3; ++cc) {
        int c = cgl * 3 + cc;
        if (c < perg * 3) {
          int g = (perg == 8) ? (c >> 3) : (c / 6);
          int jj = (perg == 8) ? (c & 7) : (c % 6);
          float bs = bias[g * dim + jb + jj];
          #pragma unroll
          for (int b = 0; b < 8; ++b) stg[set][c * 8 + b] = acc[cc][b] + bs;
        }
      }
    }
  };

  auto stats_add = [&](float* sl, int set, int perg) {
    if (tid < 24) {
      int g = tid >> 3, b = tid & 7;
      float s1 = 0.f, s2 = 0.f;
      for (int jj = 0; jj < perg; ++jj) {
        float v = stg[set][(g * perg + jj) * 8 + b];
        s1 += v; s2 += v * v;
      }
      unsafeAtomicAdd(&sl[set * 48 + g * 16 + b * 2 + 0], s1);
      unsafeAtomicAdd(&sl[set * 48 + g * 16 + b * 2 + 1], s2);
    }
  };

  auto gate_low = [&](const float* sl, bool isA) {
    if (tid < 64) {
      int jj = tid & 7, b = tid >> 3; int j = lj8 + jj;
      float xin[3], hin[3];
      #pragma unroll
      for (int g = 0; g < 3; ++g) {
        int c = g * 8 + jj;
        if (isA) {
          float m = sl[g * 16 + b * 2] * (1.f / 1024.f);
          float q = sl[g * 16 + b * 2 + 1] * (1.f / 1024.f);
          float rs = rsqrtf(q - m * m + EPSV);
          float v = (stg[0][c * 8 + b] - m) * rs * P.llig[g * 1024 + j] + P.llib[g * 1024 + j];
          xiNs[c * 8 + b] = v; xin[g] = v;
        } else {
          xin[g] = xiNs[c * 8 + b];
        }
        float m = sl[48 + g * 16 + b * 2] * (1.f / 1024.f);
        float q = sl[48 + g * 16 + b * 2 + 1] * (1.f / 1024.f);
        float rs = rsqrtf(q - m * m + EPSV);
        hin[g] = (stg[1][c * 8 + b] - m) * rs * P.llhg[g * 1024 + j] + P.llhb[g * 1024 + j];
      }
      float rg = sigm(xin[0] + hin[0]);
      float zg = sigm(xin[1] + hin[1]);
      float ng = tanh_f(xin[2] + rg * hin[2]);
      float hold = Bb[b * 1536 + swz(j)];
      ast(&P.hl[b * 1024 + j], (1.f - zg) * ng + zg * hold);
    }
  };

  auto gate_high = [&](const float* sl, int t, int nn) {
    if (tid < 48) {
      int jj = tid % 6, b = tid / 6; int j = lj6 + jj;
      float xin[3], hin[3];
      #pragma unroll
      for (int g = 0; g < 3; ++g) {
        int c = g * 6 + jj;
        float m = sl[g * 16 + b * 2] * (1.f / 768.f);
        float q = sl[g * 16 + b * 2 + 1] * (1.f / 768.f);
        float rs = rsqrtf(q - m * m + EPSV);
        xin[g] = (stg[0][c * 8 + b] - m) * rs * P.hlig[g * 768 + j] + P.hlib[g * 768 + j];
        float m2 = sl[48 + g * 16 + b * 2] * (1.f / 768.f);
        float q2 = sl[48 + g * 16 + b * 2 + 1] * (1.f / 768.f);
        float rs2 = rsqrtf(q2 - m2 * m2 + EPSV);
        hin[g] = (stg[1][c * 8 + b] - m2) * rs2 * P.hlhg[g * 768 + j] + P.hlhb[g * 768 + j];
      }
      float rg = sigm(xin[0] + hin[0]);
      float zg = sigm(xin[1] + hin[1]);
      float ng = tanh_f(xin[2] + rg * hin[2]);
      float hold = Bb[b * 1536 + swz(j)];
      float hv = (1.f - zg) * ng + zg * hold;
      ast(&P.hh[b * 768 + j], hv);
      ast(&P.xcat[b * 1536 + 768 + j], hv);
      if (nn == 2) P.hist[((size_t)t * 8 + b) * 768 + j] = __float2bfloat16(hv);
    }
  };

  // x_t = LN(emb[ids[:,tt]]) -> xcat[:, 0:768] (this WG's 6-col slice)
  auto xfun = [&](int tt) {
    int b = tid >> 5, u = tid & 31;
    int id = P.ids[b * 256 + tt];
    const float* e = P.emb + (size_t)id * 768;
    float s1 = 0.f, s2 = 0.f;
    #pragma unroll
    for (int q = 0; q < 24; q += 4) {
      float4 v = *(const float4*)&e[u * 24 + q];
      s1 += v.x + v.y + v.z + v.w;
      s2 += v.x*v.x + v.y*v.y + v.z*v.z + v.w*v.w;
    }
    #pragma unroll
    for (int m = 1; m < 32; m <<= 1) { s1 += __shfl_xor(s1, m, 64); s2 += __shfl_xor(s2, m, 64); }
    if (u == 0) { float mm = s1 / 768.f; xm[b] = mm; xrs[b] = rsqrtf(s2 / 768.f - mm * mm + EPSV); }
    __syncthreads();
    if (tid < 48) {
      int jj = tid % 6, b2 = tid / 6; int j = lj6 + jj;
      int id2 = P.ids[b2 * 256 + tt];
      float v = P.emb[(size_t)id2 * 768 + j];
      ast(&P.xcat[b2 * 1536 + j], (v - xm[b2]) * xrs[b2] * P.lng[j] + P.lnb[j]);
    }
  };

  // =================== prologue ===================
  // transpose this WG's column-slices into k-contiguous ws layouts
  #pragma unroll 1
  for (int g = 0; g < 3; ++g)
    for (int it = 0; it < 6; ++it) {   // low_Wi [3][1536][1024] -> WiT[g][j][k]
      int k = it * 256 + tid;
      const float* src = P.lWi + ((size_t)g * 1536 + k) * 1024 + lj8;
      float4 v0 = *(const float4*)src; float4 v1 = *(const float4*)(src + 4);
      float vv[8] = {v0.x, v0.y, v0.z, v0.w, v1.x, v1.y, v1.z, v1.w};
      for (int jj = 0; jj < 8; ++jj)
        P.WiT[((size_t)g * 1024 + lj8 + jj) * 1536 + k] = vv[jj];
    }
  #pragma unroll 1
  for (int g = 0; g < 3; ++g)
    for (int it = 0; it < 4; ++it) {   // high_Wi [3][1024][768] -> hWiT[g][j][k]
      int k = it * 256 + tid;
      const float* src = P.hWi + ((size_t)g * 1024 + k) * 768 + lj6;
      float2 a = *(const float2*)src, b2v = *(const float2*)(src + 2), c2v = *(const float2*)(src + 4);
      float vv[6] = {a.x, a.y, b2v.x, b2v.y, c2v.x, c2v.y};
      for (int jj = 0; jj < 6; ++jj)
        P.hWiT[((size_t)g * 768 + lj6 + jj) * 1024 + k] = vv[jj];
    }
  #pragma unroll 1
  for (int g = 0; g < 3; ++g)
    for (int it = 0; it < 3; ++it) {   // high_Wh [3][768][768] -> hWhT[g][j][k]
      int k = it * 256 + tid;
      const float* src = P.hWh + ((size_t)g * 768 + k) * 768 + lj6;
      float2 a = *(const float2*)src, b2v = *(const float2*)(src + 2), c2v = *(const float2*)(src + 4);
      float vv[6] = {a.x, a.y, b2v.x, b2v.y, c2v.x, c2v.y};
      for (int jj = 0; jj < 6; ++jj)
        P.hWhT[((size_t)g * 768 + lj6 + jj) * 768 + k] = vv[jj];
    }
  #pragma unroll 1
  for (int g = 0; g < 3; ++g)
    for (int it = 0; it < 4; ++it) {   // low_Wh slice -> LDS (swizzled)
      int k = it * 256 + tid;
      const float* src = P.lWh + ((size_t)g * 1024 + k) * 1024 + lj8;
      float4 v0 = *(const float4*)src; float4 v1 = *(const float4*)(src + 4);
      float vv[8] = {v0.x, v0.y, v0.z, v0.w, v1.x, v1.y, v1.z, v1.w};
      int sk = swz(k);
      for (int jj = 0; jj < 8; ++jj) WhS[(g * 8 + jj) * 1024 + sk] = vv[jj];
    }
  xfun(0);
  bool alive = wgbar(P.cnt + 1);   // prologue barrier (slot of round 0, phase B)

  // =================== main recurrence ===================
  int r = 0;
  #pragma unroll 1
  for (int t = 0; alive && t < 256; ++t) {
    #pragma unroll 1
    for (int nn = 0; nn < 3; ++nn) {
      // ---- round A: xi (once per n) + inner iteration 1 ----
      ++r;
      float* sl = P.stats + (size_t)96 * r;
      {
        float accX[3][8] = {}; float accH[3][8] = {};
        stage_xcat(); __syncthreads();
        gemm_xi(accX);
        redstage(accX, 0, P.lbi, 1024, 8, lj8);
        __syncthreads();
        stage_hl(); __syncthreads();
        gemm_lowh(accH);
        redstage(accH, 1, P.lbh, 1024, 8, lj8);
        __syncthreads();
        stats_add(sl, 0, 8); stats_add(sl, 1, 8);
        alive = wgbar(P.cnt + 2 * r); if (!alive) break;
        gate_low(sl, true);
        alive = wgbar(P.cnt + 2 * r + 1); if (!alive) break;
      }
      // ---- inner iterations 2..5 ----
      #pragma unroll 1
      for (int it = 1; it < 5; ++it) {
        ++r;
        sl = P.stats + (size_t)96 * r;
        float acc2[3][8] = {};
        stage_hl(); __syncthreads();
        gemm_lowh(acc2);
        redstage(acc2, 1, P.lbh, 1024, 8, lj8);
        __syncthreads();
        stats_add(sl, 1, 8);
        alive = wgbar(P.cnt + 2 * r); if (!alive) break;
        gate_low(sl, false);
        alive = wgbar(P.cnt + 2 * r + 1); if (!alive) break;
      }
      if (!alive) break;
      // ---- high GRU round ----
      ++r;
      sl = P.stats + (size_t)96 * r;
      {
        float aX[3][8] = {}; float aH[3][8] = {};
        stage_hl(); __syncthreads();
        gemm_hxi(aX);
        redstage(aX, 0, P.hbi, 768, 6, lj6);
        __syncthreads();
        stage_hh(); __syncthreads();
        gemm_hhh(aH);
        redstage(aH, 1, P.hbh, 768, 6, lj6);
        __syncthreads();
        stats_add(sl, 0, 6); stats_add(sl, 1, 6);
        alive = wgbar(P.cnt + 2 * r); if (!alive) break;
        gate_high(sl, t, nn);
        if (nn == 2 && t < 255) { __syncthreads(); xfun(t + 1); }
        alive = wgbar(P.cnt + 2 * r + 1); if (!alive) break;
      }
    }
  }
}

// =================== Wout transpose + bf16 convert ===================
__global__ void __launch_bounds__(256) wout_t(const float* __restrict__ W,
                                              __hip_bfloat16* __restrict__ WT) {
  __shared__ float T[64][65];
  int n0 = blockIdx.x * 64, k0 = blockIdx.y * 64;
  int tid = threadIdx.x;
  int lane16 = tid & 15, grp = tid >> 4;
  #pragma unroll
  for (int i = 0; i < 4; ++i) {
    int kl = i * 16 + grp; int nl = lane16 * 4;
    float4 v = *(const float4*)&W[(size_t)(k0 + kl) * 32000 + n0 + nl];
    T[kl][nl] = v.x; T[kl][nl + 1] = v.y; T[kl][nl + 2] = v.z; T[kl][nl + 3] = v.w;
  }
  __syncthreads();
  #pragma unroll
  for (int i = 0; i < 4; ++i) {
    int nl = i * 16 + grp; int kl = lane16 * 4;
    union { ushort4 v; __hip_bfloat16 h[4]; } u;
    for (int q = 0; q < 4; ++q) u.h[q] = __float2bfloat16(T[kl + q][nl]);
    *(ushort4*)&WT[(size_t)(n0 + nl) * 768 + k0 + kl] = u.v;
  }
}

// =================== logits GEMM: [2048,768] x [768,32000]^T-stored ===================
__global__ void __launch_bounds__(256) logits_gemm(const __hip_bfloat16* __restrict__ Ah,
                                                   const __hip_bfloat16* __restrict__ Bt,
                                                   const float* __restrict__ bias,
                                                   float* __restrict__ out) {
  __shared__ short As[128 * 64];
  __shared__ short Bs[128 * 64];
  int m0 = blockIdx.y * 128, n0 = blockIdx.x * 128;
  int tid = threadIdx.x, lane = tid & 63, w = tid >> 6;
  int wr = w >> 1, wc = w & 1;
  int r16 = lane & 15, khalf = (lane >> 4) * 8;
  f32x4 acc[4][4];
  #pragma unroll
  for (int i = 0; i < 4; ++i)
    #pragma unroll
    for (int j = 0; j < 4; ++j)
      #pragma unroll
      for (int q = 0; q < 4; ++q) acc[i][j][q] = 0.f;

  for (int kt = 0; kt < 12; ++kt) {
    int k0 = kt * 64;
    __syncthreads();
    #pragma unroll
    for (int it = 0; it < 4; ++it) {
      int f = it * 2048 + tid * 8; int row = f >> 6, col = f & 63;
      *(uint4*)&As[f] = *(const uint4*)&Ah[(size_t)(m0 + row) * 768 + k0 + col];
      *(uint4*)&Bs[f] = *(const uint4*)&Bt[(size_t)(n0 + row) * 768 + k0 + col];
    }
    __syncthreads();
    #pragma unroll
    for (int kk = 0; kk < 64; kk += 32) {
      short8 af[4], bfr[4];
      #pragma unroll
      for (int i = 0; i < 4; ++i)
        af[i] = *(short8*)&As[(wr * 64 + i * 16 + r16) * 64 + kk + khalf];
      #pragma unroll
      for (int j = 0; j < 4; ++j)
        bfr[j] = *(short8*)&Bs[(wc * 64 + j * 16 + r16) * 64 + kk + khalf];
      #pragma unroll
      for (int i = 0; i < 4; ++i)
        #pragma unroll
        for (int j = 0; j < 4; ++j)
          acc[i][j] = __builtin_amdgcn_mfma_f32_16x16x32_bf16(af[i], bfr[j], acc[i][j], 0, 0, 0);
    }
  }
  // C/D layout: col = lane&15, row = (lane>>4)*4 + q.  hist row m = t*8+b.
  #pragma unroll
  for (int i = 0; i < 4; ++i)
    #pragma unroll
    for (int j = 0; j < 4; ++j)
      #pragma unroll
      for (int q = 0; q < 4; ++q) {
        int m = m0 + wr * 64 + i * 16 + ((lane >> 4) * 4 + q);
        int n = n0 + wc * 64 + j * 16 + (lane & 15);
        out[(size_t)(m & 7) * 8192000 + (size_t)(m >> 3) * 32000 + n] =
            acc[i][j][q] + bias[n];
      }
}

extern "C" void kernel_launch(void* const* d_in, const int* in_sizes, int n_in,
                              void* d_out, int out_size, void* d_ws, size_t ws_size,
                              hipStream_t stream) {
  (void)in_sizes; (void)n_in; (void)out_size; (void)ws_size;
  char* wsb = (char*)d_ws;
  size_t off = 0;
  auto take = [&](size_t bytes) -> void* {
    void* p = wsb + off;
    off += (bytes + 1023) & ~(size_t)1023;
    return p;
  };
  int* cnt      = (int*)take((size_t)2 * (NROUND + 1) * 4);
  float* stats  = (float*)take((size_t)(NROUND + 1) * 96 * 4);
  float* hl     = (float*)take((size_t)8 * 1024 * 4);
  float* hh     = (float*)take((size_t)8 * 768 * 4);
  float* xcat   = (float*)take((size_t)8 * 1536 * 4);
  size_t state_bytes = off;
  __hip_bfloat16* hist = (__hip_bfloat16*)take((size_t)2048 * 768 * 2);
  float* WiT    = (float*)take((size_t)3 * 1024 * 1536 * 4);
  float* hWiT   = (float*)take((size_t)3 * 768 * 1024 * 4);
  float* hWhT   = (float*)take((size_t)3 * 768 * 768 * 4);
  __hip_bfloat16* WoutT = (__hip_bfloat16*)take((size_t)32000 * 768 * 2);
  // total ws use ~90 MB

  hipMemsetAsync(d_ws, 0, state_bytes, stream);  // counters/stats/h-state = 0

  wout_t<<<dim3(500, 12), 256, 0, stream>>>((const float*)d_in[20], WoutT);

  PArgs A;
  A.ids = (const int*)d_in[0];   A.emb = (const float*)d_in[1];
  A.lng = (const float*)d_in[2]; A.lnb = (const float*)d_in[3];
  A.lWi = (const float*)d_in[4]; A.lbi = (const float*)d_in[5];
  A.lWh = (const float*)d_in[6]; A.lbh = (const float*)d_in[7];
  A.llig = (const float*)d_in[8];  A.llib = (const float*)d_in[9];
  A.llhg = (const float*)d_in[10]; A.llhb = (const float*)d_in[11];
  A.hWi = (const float*)d_in[12];  A.hbi = (const float*)d_in[13];
  A.hWh = (const float*)d_in[14];  A.hbh = (const float*)d_in[15];
  A.hlig = (const float*)d_in[16]; A.hlib = (const float*)d_in[17];
  A.hlhg = (const float*)d_in[18]; A.hlhb = (const float*)d_in[19];
  A.cnt = cnt; A.stats = stats; A.hl = hl; A.hh = hh; A.xcat = xcat;
  A.hist = hist; A.WiT = WiT; A.hWiT = hWiT; A.hWhT = hWhT;

  hrm_recur<<<NWG, NTH, 0, stream>>>(A);

  logits_gemm<<<dim3(250, 16), 256, 0, stream>>>(hist, WoutT,
                                                 (const float*)d_in[21],
                                                 (float*)d_out);
}

// Round 2
// 90693.652 us; speedup vs baseline: 1.3338x; 1.3338x over previous
//
#include <hip/hip_runtime.h>
#include <hip/hip_bf16.h>

// HRM-LM on MI355X.
// Persistent cooperative kernel (128 WGs, 1/CU) runs the serial recurrence
// with low_Wh resident in LDS. Cross-WG traffic (h, stats) goes through
// agent-scope (sc1, LLC-coherent) atomic loads/stores -- NO acquire/release
// fences, so read-only weights stay warm in per-XCD L2. Device barrier =
// 8 group counters in a self-resetting ring of 4 slots. h_h history logged
// as bf16; logits via one deferred bf16 MFMA GEMM [2048,768]x[768,32000].

#define NWG 128
#define NTH 256
#define EPSV 1e-5f

typedef __attribute__((ext_vector_type(4))) float f32x4;
typedef __attribute__((ext_vector_type(8))) short short8;

struct PArgs {
  const int* ids; const float* emb; const float* lng; const float* lnb;
  const float* lWi; const float* lbi; const float* lWh; const float* lbh;
  const float* llig; const float* llib; const float* llhg; const float* llhb;
  const float* hWi; const float* hbi; const float* hWh; const float* hbh;
  const float* hlig; const float* hlib; const float* hlhg; const float* hlhb;
  int* cnt; float* stats; float* hl; float* hh; float* xcat;
  __hip_bfloat16* hist; float* WiT; float* hWiT; float* hWhT;
};

__device__ __forceinline__ float sigm(float x) { return 1.f / (1.f + __expf(-x)); }
__device__ __forceinline__ float tanh_f(float x) {
  x = fminf(15.f, fmaxf(-15.f, x));
  float e = __expf(2.f * x);
  return (e - 1.f) / (e + 1.f);
}
// agent-scope (device-coherent, sc1) store / load: bypass non-coherent L2.
__device__ __forceinline__ void ast(float* p, float v) {
  __hip_atomic_store(p, v, __ATOMIC_RELAXED, __HIP_MEMORY_SCOPE_AGENT);
}
__device__ __forceinline__ float ald(const float* p) {
  return __hip_atomic_load(p, __ATOMIC_RELAXED, __HIP_MEMORY_SCOPE_AGENT);
}

__global__ void __launch_bounds__(NTH) hrm_recur(PArgs P) {
  __shared__ float WhS[24 * 1024];   // low_Wh slice [c=g*8+jj][k]
  __shared__ float Bb[8 * 1536];     // B-operand staging [b][k]
  __shared__ float xiNs[24 * 8];     // normalized xi, kept across inner iters
  __shared__ float stg[2][24 * 8];   // raw (bias-added) GEMM outputs
  __shared__ float sred[96];         // reduced LN stats
  __shared__ float xm[8], xrs[8];
  __shared__ int okf;

  const int wg = blockIdx.x, tid = threadIdx.x;
  const int ks = tid & 31, cg = tid >> 5;
  const int lj8 = wg * 8, lj6 = wg * 6;

  // ---- device barrier: ring of 4 slots x 8 group-counters (64B apart) ----
  auto wgbar = [&](int b_id) -> bool {
    __syncthreads();  // drains vmcnt -> all sc1 stores at LLC before arrival
    int* slot  = P.cnt + (b_id & 3) * 128;
    int* slotR = P.cnt + ((b_id + 2) & 3) * 128;
    if (tid == 0) {
      // reset the slot that barrier b_id+2 will use (nobody can touch it now)
      __hip_atomic_store(slotR + (wg & 7) * 16, 0, __ATOMIC_RELAXED, __HIP_MEMORY_SCOPE_AGENT);
      __hip_atomic_fetch_add(slot + (wg & 7) * 16, 1, __ATOMIC_RELAXED, __HIP_MEMORY_SCOPE_AGENT);
      int lim = 1 << 20, s = 0;
      do {
        s = 0;
        #pragma unroll
        for (int g = 0; g < 8; ++g)
          s += __hip_atomic_load(slot + g * 16, __ATOMIC_RELAXED, __HIP_MEMORY_SCOPE_AGENT);
      } while (s < NWG && --lim);
      okf = (s >= NWG);
    }
    __syncthreads();
    return okf != 0;
  };

  // ---- staging via agent loads (fresh from LLC), conflict-free LDS writes ----
  auto stage_hl = [&]() {
    float4 t[8];
    #pragma unroll
    for (int i = 0; i < 8; ++i) {
      const float* p = &P.hl[i * 1024 + tid * 4];
      t[i].x = ald(p); t[i].y = ald(p + 1); t[i].z = ald(p + 2); t[i].w = ald(p + 3);
    }
    #pragma unroll
    for (int i = 0; i < 8; ++i) *(float4*)&Bb[i * 1536 + tid * 4] = t[i];
  };
  auto stage_xcat = [&]() {
    float4 t[12]; int bi[12], ki[12];
    #pragma unroll
    for (int i = 0; i < 12; ++i) {
      int c = i * 256 + tid; int b = c / 384; int k = (c - b * 384) * 4;
      bi[i] = b; ki[i] = k;
      const float* p = &P.xcat[b * 1536 + k];
      t[i].x = ald(p); t[i].y = ald(p + 1); t[i].z = ald(p + 2); t[i].w = ald(p + 3);
    }
    #pragma unroll
    for (int i = 0; i < 12; ++i) *(float4*)&Bb[bi[i] * 1536 + ki[i]] = t[i];
  };
  auto stage_hh = [&]() {
    float4 t[6]; int bi[6], ki[6];
    #pragma unroll
    for (int i = 0; i < 6; ++i) {
      int c = i * 256 + tid; int b = c / 192; int k = (c - b * 192) * 4;
      bi[i] = b; ki[i] = k;
      const float* p = &P.hh[b * 768 + k];
      t[i].x = ald(p); t[i].y = ald(p + 1); t[i].z = ald(p + 2); t[i].w = ald(p + 3);
    }
    #pragma unroll
    for (int i = 0; i < 6; ++i) *(float4*)&Bb[bi[i] * 1536 + ki[i]] = t[i];
  };

  // ---- GEMMs: thread (cg,ks) owns 3 gate-cols, k-chunks k = i*128 + ks*4 ----
  auto gemm_lowh = [&](float (&acc)[3][8]) {
    const int c0 = cg * 3;
    const float* w0p = &WhS[(c0 + 0) * 1024];
    const float* w1p = &WhS[(c0 + 1) * 1024];
    const float* w2p = &WhS[(c0 + 2) * 1024];
    #pragma unroll
    for (int i = 0; i < 8; ++i) {
      int k = i * 128 + ks * 4;
      float4 w0 = *(const float4*)&w0p[k];
      float4 w1 = *(const float4*)&w1p[k];
      float4 w2 = *(const float4*)&w2p[k];
      #pragma unroll
      for (int b = 0; b < 8; ++b) {
        float4 h = *(const float4*)&Bb[b * 1536 + k];
        acc[0][b] += w0.x*h.x + w0.y*h.y + w0.z*h.z + w0.w*h.w;
        acc[1][b] += w1.x*h.x + w1.y*h.y + w1.z*h.z + w1.w*h.w;
        acc[2][b] += w2.x*h.x + w2.y*h.y + w2.z*h.z + w2.w*h.w;
      }
    }
  };
  auto gemm_xi = [&](float (&acc)[3][8]) {
    const float* wp[3];
    #pragma unroll
    for (int cc = 0; cc < 3; ++cc) {
      int c = cg * 3 + cc; int g = c >> 3, jj = c & 7;
      wp[cc] = P.WiT + ((size_t)g * 1024 + lj8 + jj) * 1536;
    }
    #pragma unroll
    for (int i = 0; i < 12; ++i) {
      int k = i * 128 + ks * 4;
      float4 w0 = *(const float4*)&wp[0][k];
      float4 w1 = *(const float4*)&wp[1][k];
      float4 w2 = *(const float4*)&wp[2][k];
      #pragma unroll
      for (int b = 0; b < 8; ++b) {
        float4 h = *(const float4*)&Bb[b * 1536 + k];
        acc[0][b] += w0.x*h.x + w0.y*h.y + w0.z*h.z + w0.w*h.w;
        acc[1][b] += w1.x*h.x + w1.y*h.y + w1.z*h.z + w1.w*h.w;
        acc[2][b] += w2.x*h.x + w2.y*h.y + w2.z*h.z + w2.w*h.w;
      }
    }
  };
  auto gemm_hxi = [&](float (&acc)[3][8]) {  // K=1024, 18 cols
    if (cg >= 6) return;
    const float* wp[3];
    #pragma unroll
    for (int cc = 0; cc < 3; ++cc) {
      int c = cg * 3 + cc; int g = c / 6, jj = c % 6;
      wp[cc] = P.hWiT + ((size_t)g * 768 + lj6 + jj) * 1024;
    }
    #pragma unroll
    for (int i = 0; i < 8; ++i) {
      int k = i * 128 + ks * 4;
      float4 w0 = *(const float4*)&wp[0][k];
      float4 w1 = *(const float4*)&wp[1][k];
      float4 w2 = *(const float4*)&wp[2][k];
      #pragma unroll
      for (int b = 0; b < 8; ++b) {
        float4 h = *(const float4*)&Bb[b * 1536 + k];
        acc[0][b] += w0.x*h.x + w0.y*h.y + w0.z*h.z + w0.w*h.w;
        acc[1][b] += w1.x*h.x + w1.y*h.y + w1.z*h.z + w1.w*h.w;
        acc[2][b] += w2.x*h.x + w2.y*h.y + w2.z*h.z + w2.w*h.w;
      }
    }
  };
  auto gemm_hhh = [&](float (&acc)[3][8]) {  // K=768, 18 cols
    if (cg >= 6) return;
    const float* wp[3];
    #pragma unroll
    for (int cc = 0; cc < 3; ++cc) {
      int c = cg * 3 + cc; int g = c / 6, jj = c % 6;
      wp[cc] = P.hWhT + ((size_t)g * 768 + lj6 + jj) * 768;
    }
    #pragma unroll
    for (int i = 0; i < 6; ++i) {
      int k = i * 128 + ks * 4;
      float4 w0 = *(const float4*)&wp[0][k];
      float4 w1 = *(const float4*)&wp[1][k];
      float4 w2 = *(const float4*)&wp[2][k];
      #pragma unroll
      for (int b = 0; b < 8; ++b) {
        float4 h = *(const float4*)&Bb[b * 1536 + k];
        acc[0][b] += w0.x*h.x + w0.y*h.y + w0.z*h.z + w0.w*h.w;
        acc[1][b] += w1.x*h.x + w1.y*h.y + w1.z*h.z + w1.w*h.w;
        acc[2][b] += w2.x*h.x + w2.y*h.y + w2.z*h.z + w2.w*h.w;
      }
    }
  };

  // k-reduce over the 32 ks-slices (intra-32-lane butterfly), leaders stage
  auto redstage = [&](float (&acc)[3][8], int set, const float* bias, int dim,
                      int perg, int jb) {
    #pragma unroll
    for (int cc = 0; cc < 3; ++cc)
      #pragma unroll
      for (int b = 0; b < 8; ++b) {
        float v = acc[cc][b];
        #pragma unroll
        for (int m = 1; m < 32; m <<= 1) v += __shfl_xor(v, m, 64);
        acc[cc][b] = v;
      }
    if ((tid & 31) == 0) {
      int cgl = tid >> 5;
      #pragma unroll
      for (int cc = 0; cc < 3; ++cc) {
        int c = cgl * 3 + cc;
        if (c < perg * 3) {
          int g = (perg == 8) ? (c >> 3) : (c / 6);
          int jj = (perg == 8) ? (c & 7) : (c % 6);
          float bs = bias[g * dim + jb + jj];
          #pragma unroll
          for (int b = 0; b < 8; ++b) stg[set][c * 8 + b] = acc[cc][b] + bs;
        }
      }
    }
  };

  // per-WG partial LN sums -> 8 replicas (16-way atomic contention only)
  auto stats_put = [&](int e, int set, int perg) {
    if (tid < 24) {
      int g = tid >> 3, b = tid & 7;
      float s1 = 0.f, s2 = 0.f;
      for (int jj = 0; jj < perg; ++jj) {
        float v = stg[set][(g * perg + jj) * 8 + b];
        s1 += v; s2 += v * v;
      }
      float* sl = P.stats + (size_t)(e * 8 + (wg & 7)) * 96 + set * 48 + tid * 2;
      unsafeAtomicAdd(sl, s1); unsafeAtomicAdd(sl + 1, s2);
    }
  };
  // zero NEXT round's stats slot (done one round early; drained at barrier A)
  auto stats_zero_next = [&](int e) {
    if (wg < 8 && tid < 96) ast(P.stats + (size_t)((e ^ 1) * 8 + wg) * 96 + tid, 0.f);
  };
  // after barrier A: sum the 8 replicas into LDS
  auto stats_reduce = [&](int e, int lo, int n) {
    if (tid < n) {
      int idx = lo + tid;
      const float* b0 = P.stats + (size_t)e * 768 + idx;
      float s = 0.f;
      #pragma unroll
      for (int rp = 0; rp < 8; ++rp) s += ald(b0 + rp * 96);
      sred[idx] = s;
    }
    __syncthreads();
  };

  auto gate_low = [&](bool isA) {
    if (tid < 64) {
      int jj = tid & 7, b = tid >> 3; int j = lj8 + jj;
      float xin[3], hin[3];
      #pragma unroll
      for (int g = 0; g < 3; ++g) {
        int c = g * 8 + jj;
        if (isA) {
          float m = sred[g * 16 + b * 2] * (1.f / 1024.f);
          float q = sred[g * 16 + b * 2 + 1] * (1.f / 1024.f);
          float rs = rsqrtf(q - m * m + EPSV);
          float v = (stg[0][c * 8 + b] - m) * rs * P.llig[g * 1024 + j] + P.llib[g * 1024 + j];
          xiNs[c * 8 + b] = v; xin[g] = v;
        } else {
          xin[g] = xiNs[c * 8 + b];
        }
        float m = sred[48 + g * 16 + b * 2] * (1.f / 1024.f);
        float q = sred[48 + g * 16 + b * 2 + 1] * (1.f / 1024.f);
        float rs = rsqrtf(q - m * m + EPSV);
        hin[g] = (stg[1][c * 8 + b] - m) * rs * P.llhg[g * 1024 + j] + P.llhb[g * 1024 + j];
      }
      float rg = sigm(xin[0] + hin[0]);
      float zg = sigm(xin[1] + hin[1]);
      float ng = tanh_f(xin[2] + rg * hin[2]);
      float hold = Bb[b * 1536 + j];
      ast(&P.hl[b * 1024 + j], (1.f - zg) * ng + zg * hold);
    }
  };

  auto gate_high = [&](int t, int nn) {
    if (tid < 48) {
      int jj = tid % 6, b = tid / 6; int j = lj6 + jj;
      float xin[3], hin[3];
      #pragma unroll
      for (int g = 0; g < 3; ++g) {
        int c = g * 6 + jj;
        float m = sred[g * 16 + b * 2] * (1.f / 768.f);
        float q = sred[g * 16 + b * 2 + 1] * (1.f / 768.f);
        float rs = rsqrtf(q - m * m + EPSV);
        xin[g] = (stg[0][c * 8 + b] - m) * rs * P.hlig[g * 768 + j] + P.hlib[g * 768 + j];
        float m2 = sred[48 + g * 16 + b * 2] * (1.f / 768.f);
        float q2 = sred[48 + g * 16 + b * 2 + 1] * (1.f / 768.f);
        float rs2 = rsqrtf(q2 - m2 * m2 + EPSV);
        hin[g] = (stg[1][c * 8 + b] - m2) * rs2 * P.hlhg[g * 768 + j] + P.hlhb[g * 768 + j];
      }
      float rg = sigm(xin[0] + hin[0]);
      float zg = sigm(xin[1] + hin[1]);
      float ng = tanh_f(xin[2] + rg * hin[2]);
      float hold = Bb[b * 1536 + j];
      float hv = (1.f - zg) * ng + zg * hold;
      ast(&P.hh[b * 768 + j], hv);
      ast(&P.xcat[b * 1536 + 768 + j], hv);
      if (nn == 2) P.hist[((size_t)t * 8 + b) * 768 + j] = __float2bfloat16(hv);
    }
  };

  // x_t = LN(emb[ids[:,tt]]) -> xcat[:, 0:768] (this WG's 6-col slice)
  auto xfun = [&](int tt) {
    int b = tid >> 5, u = tid & 31;
    int id = P.ids[b * 256 + tt];
    const float* e = P.emb + (size_t)id * 768;
    float s1 = 0.f, s2 = 0.f;
    #pragma unroll
    for (int q = 0; q < 24; q += 4) {
      float4 v = *(const float4*)&e[u * 24 + q];
      s1 += v.x + v.y + v.z + v.w;
      s2 += v.x*v.x + v.y*v.y + v.z*v.z + v.w*v.w;
    }
    #pragma unroll
    for (int m = 1; m < 32; m <<= 1) { s1 += __shfl_xor(s1, m, 64); s2 += __shfl_xor(s2, m, 64); }
    if (u == 0) { float mm = s1 / 768.f; xm[b] = mm; xrs[b] = rsqrtf(s2 / 768.f - mm * mm + EPSV); }
    __syncthreads();
    if (tid < 48) {
      int jj = tid % 6, b2 = tid / 6; int j = lj6 + jj;
      int id2 = P.ids[b2 * 256 + tt];
      float v = P.emb[(size_t)id2 * 768 + j];
      ast(&P.xcat[b2 * 1536 + j], (v - xm[b2]) * xrs[b2] * P.lng[j] + P.lnb[j]);
    }
  };

  // =================== prologue ===================
  #pragma unroll 1
  for (int g = 0; g < 3; ++g)
    for (int it = 0; it < 6; ++it) {   // low_Wi [3][1536][1024] -> WiT[g][j][k]
      int k = it * 256 + tid;
      const float* src = P.lWi + ((size_t)g * 1536 + k) * 1024 + lj8;
      float4 v0 = *(const float4*)src; float4 v1 = *(const float4*)(src + 4);
      float vv[8] = {v0.x, v0.y, v0.z, v0.w, v1.x, v1.y, v1.z, v1.w};
      for (int jj = 0; jj < 8; ++jj)
        P.WiT[((size_t)g * 1024 + lj8 + jj) * 1536 + k] = vv[jj];
    }
  #pragma unroll 1
  for (int g = 0; g < 3; ++g)
    for (int it = 0; it < 4; ++it) {   // high_Wi [3][1024][768] -> hWiT[g][j][k]
      int k = it * 256 + tid;
      const float* src = P.hWi + ((size_t)g * 1024 + k) * 768 + lj6;
      float2 a = *(const float2*)src, b2v = *(const float2*)(src + 2), c2v = *(const float2*)(src + 4);
      float vv[6] = {a.x, a.y, b2v.x, b2v.y, c2v.x, c2v.y};
      for (int jj = 0; jj < 6; ++jj)
        P.hWiT[((size_t)g * 768 + lj6 + jj) * 1024 + k] = vv[jj];
    }
  #pragma unroll 1
  for (int g = 0; g < 3; ++g)
    for (int it = 0; it < 3; ++it) {   // high_Wh [3][768][768] -> hWhT[g][j][k]
      int k = it * 256 + tid;
      const float* src = P.hWh + ((size_t)g * 768 + k) * 768 + lj6;
      float2 a = *(const float2*)src, b2v = *(const float2*)(src + 2), c2v = *(const float2*)(src + 4);
      float vv[6] = {a.x, a.y, b2v.x, b2v.y, c2v.x, c2v.y};
      for (int jj = 0; jj < 6; ++jj)
        P.hWhT[((size_t)g * 768 + lj6 + jj) * 768 + k] = vv[jj];
    }
  #pragma unroll 1
  for (int g = 0; g < 3; ++g)
    for (int it = 0; it < 4; ++it) {   // low_Wh slice -> LDS
      int k = it * 256 + tid;
      const float* src = P.lWh + ((size_t)g * 1024 + k) * 1024 + lj8;
      float4 v0 = *(const float4*)src; float4 v1 = *(const float4*)(src + 4);
      float vv[8] = {v0.x, v0.y, v0.z, v0.w, v1.x, v1.y, v1.z, v1.w};
      for (int jj = 0; jj < 8; ++jj) WhS[(g * 8 + jj) * 1024 + k] = vv[jj];
    }
  xfun(0);
  int bid = 0;
  bool alive = wgbar(bid++);   // prologue barrier

  // =================== main recurrence ===================
  int r = 0;
  #pragma unroll 1
  for (int t = 0; alive && t < 256; ++t) {
    #pragma unroll 1
    for (int nn = 0; nn < 3; ++nn) {
      // ---- round A: xi (once per n) + inner iteration 1 ----
      ++r;
      int e = r & 1;
      {
        stats_zero_next(e);
        float accX[3][8] = {}; float accH[3][8] = {};
        stage_xcat(); __syncthreads();
        gemm_xi(accX);
        redstage(accX, 0, P.lbi, 1024, 8, lj8);
        __syncthreads();
        stage_hl(); __syncthreads();
        gemm_lowh(accH);
        redstage(accH, 1, P.lbh, 1024, 8, lj8);
        __syncthreads();
        stats_put(e, 0, 8); stats_put(e, 1, 8);
        alive = wgbar(bid++); if (!alive) break;
        stats_reduce(e, 0, 96);
        gate_low(true);
        alive = wgbar(bid++); if (!alive) break;
      }
      // ---- inner iterations 2..5 ----
      #pragma unroll 1
      for (int it = 1; it < 5; ++it) {
        ++r;
        e = r & 1;
        stats_zero_next(e);
        float acc2[3][8] = {};
        stage_hl(); __syncthreads();
        gemm_lowh(acc2);
        redstage(acc2, 1, P.lbh, 1024, 8, lj8);
        __syncthreads();
        stats_put(e, 1, 8);
        alive = wgbar(bid++); if (!alive) break;
        stats_reduce(e, 48, 48);
        gate_low(false);
        alive = wgbar(bid++); if (!alive) break;
      }
      if (!alive) break;
      // ---- high GRU round ----
      ++r;
      e = r & 1;
      {
        stats_zero_next(e);
        float aX[3][8] = {}; float aH[3][8] = {};
        stage_hl(); __syncthreads();
        gemm_hxi(aX);
        redstage(aX, 0, P.hbi, 768, 6, lj6);
        __syncthreads();
        stage_hh(); __syncthreads();
        gemm_hhh(aH);
        redstage(aH, 1, P.hbh, 768, 6, lj6);
        __syncthreads();
        stats_put(e, 0, 6); stats_put(e, 1, 6);
        alive = wgbar(bid++); if (!alive) break;
        stats_reduce(e, 0, 96);
        gate_high(t, nn);
        if (nn == 2 && t < 255) { __syncthreads(); xfun(t + 1); }
        alive = wgbar(bid++); if (!alive) break;
      }
    }
  }
}

// =================== Wout transpose + bf16 convert ===================
__global__ void __launch_bounds__(256) wout_t(const float* __restrict__ W,
                                              __hip_bfloat16* __restrict__ WT) {
  __shared__ float T[64][65];
  int n0 = blockIdx.x * 64, k0 = blockIdx.y * 64;
  int tid = threadIdx.x;
  int lane16 = tid & 15, grp = tid >> 4;
  #pragma unroll
  for (int i = 0; i < 4; ++i) {
    int kl = i * 16 + grp; int nl = lane16 * 4;
    float4 v = *(const float4*)&W[(size_t)(k0 + kl) * 32000 + n0 + nl];
    T[kl][nl] = v.x; T[kl][nl + 1] = v.y; T[kl][nl + 2] = v.z; T[kl][nl + 3] = v.w;
  }
  __syncthreads();
  #pragma unroll
  for (int i = 0; i < 4; ++i) {
    int nl = i * 16 + grp; int kl = lane16 * 4;
    union { ushort4 v; __hip_bfloat16 h[4]; } u;
    for (int q = 0; q < 4; ++q) u.h[q] = __float2bfloat16(T[kl + q][nl]);
    *(ushort4*)&WT[(size_t)(n0 + nl) * 768 + k0 + kl] = u.v;
  }
}

// =================== logits GEMM: [2048,768] x [768,32000]^T-stored ===================
__global__ void __launch_bounds__(256) logits_gemm(const __hip_bfloat16* __restrict__ Ah,
                                                   const __hip_bfloat16* __restrict__ Bt,
                                                   const float* __restrict__ bias,
                                                   float* __restrict__ out) {
  __shared__ short As[128 * 64];
  __shared__ short Bs[128 * 64];
  int m0 = blockIdx.y * 128, n0 = blockIdx.x * 128;
  int tid = threadIdx.x, lane = tid & 63, w = tid >> 6;
  int wr = w >> 1, wc = w & 1;
  int r16 = lane & 15, khalf = (lane >> 4) * 8;
  f32x4 acc[4][4];
  #pragma unroll
  for (int i = 0; i < 4; ++i)
    #pragma unroll
    for (int j = 0; j < 4; ++j)
      #pragma unroll
      for (int q = 0; q < 4; ++q) acc[i][j][q] = 0.f;

  for (int kt = 0; kt < 12; ++kt) {
    int k0 = kt * 64;
    __syncthreads();
    #pragma unroll
    for (int it = 0; it < 4; ++it) {
      int f = it * 2048 + tid * 8; int row = f >> 6, col = f & 63;
      *(uint4*)&As[f] = *(const uint4*)&Ah[(size_t)(m0 + row) * 768 + k0 + col];
      *(uint4*)&Bs[f] = *(const uint4*)&Bt[(size_t)(n0 + row) * 768 + k0 + col];
    }
    __syncthreads();
    #pragma unroll
    for (int kk = 0; kk < 64; kk += 32) {
      short8 af[4], bfr[4];
      #pragma unroll
      for (int i = 0; i < 4; ++i)
        af[i] = *(short8*)&As[(wr * 64 + i * 16 + r16) * 64 + kk + khalf];
      #pragma unroll
      for (int j = 0; j < 4; ++j)
        bfr[j] = *(short8*)&Bs[(wc * 64 + j * 16 + r16) * 64 + kk + khalf];
      #pragma unroll
      for (int i = 0; i < 4; ++i)
        #pragma unroll
        for (int j = 0; j < 4; ++j)
          acc[i][j] = __builtin_amdgcn_mfma_f32_16x16x32_bf16(af[i], bfr[j], acc[i][j], 0, 0, 0);
    }
  }
  #pragma unroll
  for (int i = 0; i < 4; ++i)
    #pragma unroll
    for (int j = 0; j < 4; ++j)
      #pragma unroll
      for (int q = 0; q < 4; ++q) {
        int m = m0 + wr * 64 + i * 16 + ((lane >> 4) * 4 + q);
        int n = n0 + wc * 64 + j * 16 + (lane & 15);
        out[(size_t)(m & 7) * 8192000 + (size_t)(m >> 3) * 32000 + n] =
            acc[i][j][q] + bias[n];
      }
}

extern "C" void kernel_launch(void* const* d_in, const int* in_sizes, int n_in,
                              void* d_out, int out_size, void* d_ws, size_t ws_size,
                              hipStream_t stream) {
  (void)in_sizes; (void)n_in; (void)out_size; (void)ws_size;
  char* wsb = (char*)d_ws;
  size_t off = 0;
  auto take = [&](size_t bytes) -> void* {
    void* p = wsb + off;
    off += (bytes + 1023) & ~(size_t)1023;
    return p;
  };
  int* cnt      = (int*)take((size_t)4 * 128 * 4);        // 4-slot barrier ring
  float* stats  = (float*)take((size_t)2 * 8 * 96 * 4);   // 2-slot x 8-replica stats
  float* hl     = (float*)take((size_t)8 * 1024 * 4);
  float* hh     = (float*)take((size_t)8 * 768 * 4);
  float* xcat   = (float*)take((size_t)8 * 1536 * 4);
  size_t state_bytes = off;   // ~116 KB
  __hip_bfloat16* hist = (__hip_bfloat16*)take((size_t)2048 * 768 * 2);
  float* WiT    = (float*)take((size_t)3 * 1024 * 1536 * 4);
  float* hWiT   = (float*)take((size_t)3 * 768 * 1024 * 4);
  float* hWhT   = (float*)take((size_t)3 * 768 * 768 * 4);
  __hip_bfloat16* WoutT = (__hip_bfloat16*)take((size_t)32000 * 768 * 2);

  hipMemsetAsync(d_ws, 0, state_bytes, stream);  // counters/stats/h-state = 0

  wout_t<<<dim3(500, 12), 256, 0, stream>>>((const float*)d_in[20], WoutT);

  PArgs A;
  A.ids = (const int*)d_in[0];   A.emb = (const float*)d_in[1];
  A.lng = (const float*)d_in[2]; A.lnb = (const float*)d_in[3];
  A.lWi = (const float*)d_in[4]; A.lbi = (const float*)d_in[5];
  A.lWh = (const float*)d_in[6]; A.lbh = (const float*)d_in[7];
  A.llig = (const float*)d_in[8];  A.llib = (const float*)d_in[9];
  A.llhg = (const float*)d_in[10]; A.llhb = (const float*)d_in[11];
  A.hWi = (const float*)d_in[12];  A.hbi = (const float*)d_in[13];
  A.hWh = (const float*)d_in[14];  A.hbh = (const float*)d_in[15];
  A.hlig = (const float*)d_in[16]; A.hlib = (const float*)d_in[17];
  A.hlhg = (const float*)d_in[18]; A.hlhb = (const float*)d_in[19];
  A.cnt = cnt; A.stats = stats; A.hl = hl; A.hh = hh; A.xcat = xcat;
  A.hist = hist; A.WiT = WiT; A.hWiT = hWiT; A.hWhT = hWhT;

  hrm_recur<<<NWG, NTH, 0, stream>>>(A);

  logits_gemm<<<dim3(250, 16), 256, 0, stream>>>(hist, WoutT,
                                                 (const float*)d_in[21],
                                                 (float*)d_out);
}

// Round 3
// 86131.244 us; speedup vs baseline: 1.4044x; 1.0530x over previous
//
#include <hip/hip_runtime.h>
#include <hip/hip_bf16.h>

// HRM-LM on MI355X.
// Persistent cooperative kernel (128 WGs, 1/CU) runs the serial recurrence
// with low_Wh resident in LDS. Cross-WG traffic (h, stats) via agent-scope
// (sc1, LLC-coherent) atomics -- no acquire fences, weights stay in L2.
// Sync: (a) LN-stats carry their own arrival counters (fine-grained sync,
// no device barrier for stats); (b) one monotonic-counter device barrier
// per round for h-state propagation. Streamed weights are L2-prefetched
// during inner rounds. h_h history logged bf16; logits via one deferred
// bf16 MFMA GEMM [2048,768]x[768,32000].

#define NWG 128
#define NTH 256
#define EPSV 1e-5f

typedef __attribute__((ext_vector_type(4))) float f32x4;
typedef __attribute__((ext_vector_type(8))) short short8;

struct PArgs {
  const int* ids; const float* emb; const float* lng; const float* lnb;
  const float* lWi; const float* lbi; const float* lWh; const float* lbh;
  const float* llig; const float* llib; const float* llhg; const float* llhb;
  const float* hWi; const float* hbi; const float* hWh; const float* hbh;
  const float* hlig; const float* hlib; const float* hlhg; const float* hlhb;
  int* cnt; int* scnt; float* stats; float* hl; float* hh; float* xcat;
  __hip_bfloat16* hist; float* WiT; float* hWiT; float* hWhT;
};

__device__ __forceinline__ float sigm(float x) { return 1.f / (1.f + __expf(-x)); }
__device__ __forceinline__ float tanh_f(float x) {
  x = fminf(15.f, fmaxf(-15.f, x));
  float e = __expf(2.f * x);
  return (e - 1.f) / (e + 1.f);
}
// agent-scope (device-coherent, sc1) stores / loads: bypass non-coherent L2.
__device__ __forceinline__ void ast(float* p, float v) {
  __hip_atomic_store(p, v, __ATOMIC_RELAXED, __HIP_MEMORY_SCOPE_AGENT);
}
__device__ __forceinline__ float ald(const float* p) {
  return __hip_atomic_load(p, __ATOMIC_RELAXED, __HIP_MEMORY_SCOPE_AGENT);
}
__device__ __forceinline__ int aldi(const int* p) {
  return __hip_atomic_load(p, __ATOMIC_RELAXED, __HIP_MEMORY_SCOPE_AGENT);
}
__device__ __forceinline__ float2 ald2(const float* p) {
  union { unsigned long long u; float2 f; } c;
  c.u = __hip_atomic_load((const unsigned long long*)p, __ATOMIC_RELAXED,
                          __HIP_MEMORY_SCOPE_AGENT);
  return c.f;
}

__global__ void __launch_bounds__(NTH) hrm_recur(PArgs P) {
  __shared__ float WhS[24 * 1024];   // low_Wh slice [c=g*8+jj][k]
  __shared__ float Bb[8 * 1536];     // B-operand staging [b][k]
  __shared__ float xiNs[24 * 8];     // normalized xi, kept across inner iters
  __shared__ float stg[2][24 * 8];   // raw (bias-added) GEMM outputs
  __shared__ float sred[96];         // reduced LN stats
  __shared__ float xm[8], xrs[8];
  __shared__ int okf;

  const int wg = blockIdx.x, tid = threadIdx.x;
  const int ks = tid & 31, cg = tid >> 5;
  const int lj8 = wg * 8, lj6 = wg * 6;

  // ---- device barrier: 8 monotonic group counters, never reset ----
  auto wgbar = [&](int target) -> bool {
    __syncthreads();  // drains vmcnt -> all sc1 stores ack'd at LLC
    if (tid == 0) {
      __hip_atomic_fetch_add(P.cnt + (wg & 7) * 32, 1, __ATOMIC_RELAXED,
                             __HIP_MEMORY_SCOPE_AGENT);
      int lim = 1 << 22, s = 0;
      for (;;) {
        s = 0;
        #pragma unroll
        for (int g = 0; g < 8; ++g) s += aldi(P.cnt + g * 32);
        if (s >= target || !--lim) break;
        __builtin_amdgcn_s_sleep(1);
      }
      okf = (s >= target);
    }
    __syncthreads();
    return okf != 0;
  };

  // ---- staging via u64 agent loads ----
  auto stage_hl = [&]() {
    float2 ta[8], tb[8];
    #pragma unroll
    for (int i = 0; i < 8; ++i) {
      const float* p = &P.hl[i * 1024 + tid * 4];
      ta[i] = ald2(p); tb[i] = ald2(p + 2);
    }
    #pragma unroll
    for (int i = 0; i < 8; ++i) {
      float4 v; v.x = ta[i].x; v.y = ta[i].y; v.z = tb[i].x; v.w = tb[i].y;
      *(float4*)&Bb[i * 1536 + tid * 4] = v;
    }
  };
  auto stage_xcat = [&]() {
    float2 ta[12], tb[12]; int bi[12], ki[12];
    #pragma unroll
    for (int i = 0; i < 12; ++i) {
      int c = i * 256 + tid; int b = c / 384; int k = (c - b * 384) * 4;
      bi[i] = b; ki[i] = k;
      const float* p = &P.xcat[b * 1536 + k];
      ta[i] = ald2(p); tb[i] = ald2(p + 2);
    }
    #pragma unroll
    for (int i = 0; i < 12; ++i) {
      float4 v; v.x = ta[i].x; v.y = ta[i].y; v.z = tb[i].x; v.w = tb[i].y;
      *(float4*)&Bb[bi[i] * 1536 + ki[i]] = v;
    }
  };
  auto stage_hh = [&]() {
    float2 ta[6], tb[6]; int bi[6], ki[6];
    #pragma unroll
    for (int i = 0; i < 6; ++i) {
      int c = i * 256 + tid; int b = c / 192; int k = (c - b * 192) * 4;
      bi[i] = b; ki[i] = k;
      const float* p = &P.hh[b * 768 + k];
      ta[i] = ald2(p); tb[i] = ald2(p + 2);
    }
    #pragma unroll
    for (int i = 0; i < 6; ++i) {
      float4 v; v.x = ta[i].x; v.y = ta[i].y; v.z = tb[i].x; v.w = tb[i].y;
      *(float4*)&Bb[bi[i] * 1536 + ki[i]] = v;
    }
  };

  // ---- GEMMs: thread (cg,ks) owns 3 gate-cols, k-chunks k = i*128 + ks*4 ----
  auto gemm_lowh = [&](float (&acc)[3][8]) {
    const int c0 = cg * 3;
    const float* w0p = &WhS[(c0 + 0) * 1024];
    const float* w1p = &WhS[(c0 + 1) * 1024];
    const float* w2p = &WhS[(c0 + 2) * 1024];
    #pragma unroll
    for (int i = 0; i < 8; ++i) {
      int k = i * 128 + ks * 4;
      float4 w0 = *(const float4*)&w0p[k];
      float4 w1 = *(const float4*)&w1p[k];
      float4 w2 = *(const float4*)&w2p[k];
      #pragma unroll
      for (int b = 0; b < 8; ++b) {
        float4 h = *(const float4*)&Bb[b * 1536 + k];
        acc[0][b] += w0.x*h.x + w0.y*h.y + w0.z*h.z + w0.w*h.w;
        acc[1][b] += w1.x*h.x + w1.y*h.y + w1.z*h.z + w1.w*h.w;
        acc[2][b] += w2.x*h.x + w2.y*h.y + w2.z*h.z + w2.w*h.w;
      }
    }
  };
  auto gemm_xi = [&](float (&acc)[3][8]) {
    const float* wp[3];
    #pragma unroll
    for (int cc = 0; cc < 3; ++cc) {
      int c = cg * 3 + cc; int g = c >> 3, jj = c & 7;
      wp[cc] = P.WiT + ((size_t)g * 1024 + lj8 + jj) * 1536;
    }
    #pragma unroll
    for (int i = 0; i < 12; ++i) {
      int k = i * 128 + ks * 4;
      float4 w0 = *(const float4*)&wp[0][k];
      float4 w1 = *(const float4*)&wp[1][k];
      float4 w2 = *(const float4*)&wp[2][k];
      #pragma unroll
      for (int b = 0; b < 8; ++b) {
        float4 h = *(const float4*)&Bb[b * 1536 + k];
        acc[0][b] += w0.x*h.x + w0.y*h.y + w0.z*h.z + w0.w*h.w;
        acc[1][b] += w1.x*h.x + w1.y*h.y + w1.z*h.z + w1.w*h.w;
        acc[2][b] += w2.x*h.x + w2.y*h.y + w2.z*h.z + w2.w*h.w;
      }
    }
  };
  auto gemm_hxi = [&](float (&acc)[3][8]) {  // K=1024, 18 cols
    if (cg >= 6) return;
    const float* wp[3];
    #pragma unroll
    for (int cc = 0; cc < 3; ++cc) {
      int c = cg * 3 + cc; int g = c / 6, jj = c % 6;
      wp[cc] = P.hWiT + ((size_t)g * 768 + lj6 + jj) * 1024;
    }
    #pragma unroll
    for (int i = 0; i < 8; ++i) {
      int k = i * 128 + ks * 4;
      float4 w0 = *(const float4*)&wp[0][k];
      float4 w1 = *(const float4*)&wp[1][k];
      float4 w2 = *(const float4*)&wp[2][k];
      #pragma unroll
      for (int b = 0; b < 8; ++b) {
        float4 h = *(const float4*)&Bb[b * 1536 + k];
        acc[0][b] += w0.x*h.x + w0.y*h.y + w0.z*h.z + w0.w*h.w;
        acc[1][b] += w1.x*h.x + w1.y*h.y + w1.z*h.z + w1.w*h.w;
        acc[2][b] += w2.x*h.x + w2.y*h.y + w2.z*h.z + w2.w*h.w;
      }
    }
  };
  auto gemm_hhh = [&](float (&acc)[3][8]) {  // K=768, 18 cols
    if (cg >= 6) return;
    const float* wp[3];
    #pragma unroll
    for (int cc = 0; cc < 3; ++cc) {
      int c = cg * 3 + cc; int g = c / 6, jj = c % 6;
      wp[cc] = P.hWhT + ((size_t)g * 768 + lj6 + jj) * 768;
    }
    #pragma unroll
    for (int i = 0; i < 6; ++i) {
      int k = i * 128 + ks * 4;
      float4 w0 = *(const float4*)&wp[0][k];
      float4 w1 = *(const float4*)&wp[1][k];
      float4 w2 = *(const float4*)&wp[2][k];
      #pragma unroll
      for (int b = 0; b < 8; ++b) {
        float4 h = *(const float4*)&Bb[b * 1536 + k];
        acc[0][b] += w0.x*h.x + w0.y*h.y + w0.z*h.z + w0.w*h.w;
        acc[1][b] += w1.x*h.x + w1.y*h.y + w1.z*h.z + w1.w*h.w;
        acc[2][b] += w2.x*h.x + w2.y*h.y + w2.z*h.z + w2.w*h.w;
      }
    }
  };

  // k-reduce over the 32 ks-slices (intra-32-lane butterfly), leaders stage
  auto redstage = [&](float (&acc)[3][8], int set, const float* bias, int dim,
                      int perg, int jb) {
    #pragma unroll
    for (int cc = 0; cc < 3; ++cc)
      #pragma unroll
      for (int b = 0; b < 8; ++b) {
        float v = acc[cc][b];
        #pragma unroll
        for (int m = 1; m < 32; m <<= 1) v += __shfl_xor(v, m, 64);
        acc[cc][b] = v;
      }
    if ((tid & 31) == 0) {
      int cgl = tid >> 5;
      #pragma unroll
      for (int cc = 0; cc < 3; ++cc) {
        int c = cgl * 3 + cc;
        if (c < perg * 3) {
          int g = (perg == 8) ? (c >> 3) : (c / 6);
          int jj = (perg == 8) ? (c & 7) : (c % 6);
          float bs = bias[g * dim + jb + jj];
          #pragma unroll
          for (int b = 0; b < 8; ++b) stg[set][c * 8 + b] = acc[cc][b] + bs;
        }
      }
    }
  };

  // per-WG partial LN sums -> 8 replicas (16-way atomic contention)
  auto stats_put = [&](int e, int set, int perg) {
    if (tid < 24) {
      int g = tid >> 3, b = tid & 7;
      float s1 = 0.f, s2 = 0.f;
      for (int jj = 0; jj < perg; ++jj) {
        float v = stg[set][(g * perg + jj) * 8 + b];
        s1 += v; s2 += v * v;
      }
      float* sl = P.stats + (size_t)(e * 8 + (wg & 7)) * 128 + set * 48 + tid * 2;
      unsafeAtomicAdd(sl, s1); unsafeAtomicAdd(sl + 1, s2);
    }
  };
  // after fp-adds ack'd, bump this replica's arrival counter (stats ARE the sync)
  auto stats_commit = [&](int e) {
    asm volatile("s_waitcnt vmcnt(0)" ::: "memory");
    if (tid == 0)
      __hip_atomic_fetch_add(P.scnt + (e * 8 + (wg & 7)) * 32, 1,
                             __ATOMIC_RELAXED, __HIP_MEMORY_SCOPE_AGENT);
  };
  // zero NEXT round's stats slot+counters (safe: ring ordered by barB)
  auto stats_zero_next = [&](int e) {
    if (wg < 8) {
      if (tid < 96) ast(P.stats + (size_t)((e ^ 1) * 8 + wg) * 128 + tid, 0.f);
      if (tid == 96)
        __hip_atomic_store(P.scnt + ((e ^ 1) * 8 + wg) * 32, 0,
                           __ATOMIC_RELAXED, __HIP_MEMORY_SCOPE_AGENT);
    }
  };
  // wait for all 8 replicas complete, then reduce into sred
  auto stats_sync = [&](int e, int lo, int n) -> bool {
    int myok = 1;
    if (tid < 8) {
      const int* cp = P.scnt + (e * 8 + tid) * 32;
      int lim = 1 << 22;
      while (aldi(cp) < 16) {
        if (!--lim) { myok = 0; break; }
        __builtin_amdgcn_s_sleep(1);
      }
    }
    int allok = __all(myok);
    if (tid == 0) okf = allok;
    __syncthreads();
    if (tid < (n >> 1)) {
      int idx = lo + tid * 2;
      const float* b0 = P.stats + (size_t)e * 1024 + idx;
      float s1 = 0.f, s2 = 0.f;
      #pragma unroll
      for (int rp = 0; rp < 8; ++rp) {
        float2 v = ald2(b0 + rp * 128);
        s1 += v.x; s2 += v.y;
      }
      sred[idx] = s1; sred[idx + 1] = s2;
    }
    __syncthreads();
    return okf != 0;
  };

  auto gate_low = [&](bool isA) {
    if (tid < 64) {
      int jj = tid & 7, b = tid >> 3; int j = lj8 + jj;
      float xin[3], hin[3];
      #pragma unroll
      for (int g = 0; g < 3; ++g) {
        int c = g * 8 + jj;
        if (isA) {
          float m = sred[g * 16 + b * 2] * (1.f / 1024.f);
          float q = sred[g * 16 + b * 2 + 1] * (1.f / 1024.f);
          float rs = rsqrtf(q - m * m + EPSV);
          float v = (stg[0][c * 8 + b] - m) * rs * P.llig[g * 1024 + j] + P.llib[g * 1024 + j];
          xiNs[c * 8 + b] = v; xin[g] = v;
        } else {
          xin[g] = xiNs[c * 8 + b];
        }
        float m = sred[48 + g * 16 + b * 2] * (1.f / 1024.f);
        float q = sred[48 + g * 16 + b * 2 + 1] * (1.f / 1024.f);
        float rs = rsqrtf(q - m * m + EPSV);
        hin[g] = (stg[1][c * 8 + b] - m) * rs * P.llhg[g * 1024 + j] + P.llhb[g * 1024 + j];
      }
      float rg = sigm(xin[0] + hin[0]);
      float zg = sigm(xin[1] + hin[1]);
      float ng = tanh_f(xin[2] + rg * hin[2]);
      float hold = Bb[b * 1536 + j];
      ast(&P.hl[b * 1024 + j], (1.f - zg) * ng + zg * hold);
    }
  };

  auto gate_high = [&](int t, int nn) {
    if (tid < 48) {
      int jj = tid % 6, b = tid / 6; int j = lj6 + jj;
      float xin[3], hin[3];
      #pragma unroll
      for (int g = 0; g < 3; ++g) {
        int c = g * 6 + jj;
        float m = sred[g * 16 + b * 2] * (1.f / 768.f);
        float q = sred[g * 16 + b * 2 + 1] * (1.f / 768.f);
        float rs = rsqrtf(q - m * m + EPSV);
        xin[g] = (stg[0][c * 8 + b] - m) * rs * P.hlig[g * 768 + j] + P.hlib[g * 768 + j];
        float m2 = sred[48 + g * 16 + b * 2] * (1.f / 768.f);
        float q2 = sred[48 + g * 16 + b * 2 + 1] * (1.f / 768.f);
        float rs2 = rsqrtf(q2 - m2 * m2 + EPSV);
        hin[g] = (stg[1][c * 8 + b] - m2) * rs2 * P.hlhg[g * 768 + j] + P.hlhb[g * 768 + j];
      }
      float rg = sigm(xin[0] + hin[0]);
      float zg = sigm(xin[1] + hin[1]);
      float ng = tanh_f(xin[2] + rg * hin[2]);
      float hold = Bb[b * 1536 + j];
      float hv = (1.f - zg) * ng + zg * hold;
      ast(&P.hh[b * 768 + j], hv);
      ast(&P.xcat[b * 1536 + 768 + j], hv);
      if (nn == 2) P.hist[((size_t)t * 8 + b) * 768 + j] = __float2bfloat16(hv);
    }
  };

  // x_t = LN(emb[ids[:,tt]]) -> xcat[:, 0:768] (this WG's 6-col slice)
  auto xfun = [&](int tt) {
    int b = tid >> 5, u = tid & 31;
    int id = P.ids[b * 256 + tt];
    const float* e = P.emb + (size_t)id * 768;
    float s1 = 0.f, s2 = 0.f;
    #pragma unroll
    for (int q = 0; q < 24; q += 4) {
      float4 v = *(const float4*)&e[u * 24 + q];
      s1 += v.x + v.y + v.z + v.w;
      s2 += v.x*v.x + v.y*v.y + v.z*v.z + v.w*v.w;
    }
    #pragma unroll
    for (int m = 1; m < 32; m <<= 1) { s1 += __shfl_xor(s1, m, 64); s2 += __shfl_xor(s2, m, 64); }
    if (u == 0) { float mm = s1 / 768.f; xm[b] = mm; xrs[b] = rsqrtf(s2 / 768.f - mm * mm + EPSV); }
    __syncthreads();
    if (tid < 48) {
      int jj = tid % 6, b2 = tid / 6; int j = lj6 + jj;
      int id2 = P.ids[b2 * 256 + tt];
      float v = P.emb[(size_t)id2 * 768 + j];
      ast(&P.xcat[b2 * 1536 + j], (v - xm[b2]) * xrs[b2] * P.lng[j] + P.lnb[j]);
    }
  };

  // L2 line-touch prefetch (normal cached loads; one float per 128B line)
  auto pf = [&](const float* base, int len, float& a) {
    #pragma unroll
    for (int i = 0; i * 8192 < len; ++i) {
      int idx = (i * 256 + tid) * 32;
      if (idx < len) a += base[idx];
    }
  };

  // =================== prologue ===================
  #pragma unroll 1
  for (int g = 0; g < 3; ++g)
    for (int it = 0; it < 6; ++it) {   // low_Wi [3][1536][1024] -> WiT[g][j][k]
      int k = it * 256 + tid;
      const float* src = P.lWi + ((size_t)g * 1536 + k) * 1024 + lj8;
      float4 v0 = *(const float4*)src; float4 v1 = *(const float4*)(src + 4);
      float vv[8] = {v0.x, v0.y, v0.z, v0.w, v1.x, v1.y, v1.z, v1.w};
      for (int jj = 0; jj < 8; ++jj)
        P.WiT[((size_t)g * 1024 + lj8 + jj) * 1536 + k] = vv[jj];
    }
  #pragma unroll 1
  for (int g = 0; g < 3; ++g)
    for (int it = 0; it < 4; ++it) {   // high_Wi [3][1024][768] -> hWiT[g][j][k]
      int k = it * 256 + tid;
      const float* src = P.hWi + ((size_t)g * 1024 + k) * 768 + lj6;
      float2 a = *(const float2*)src, b2v = *(const float2*)(src + 2), c2v = *(const float2*)(src + 4);
      float vv[6] = {a.x, a.y, b2v.x, b2v.y, c2v.x, c2v.y};
      for (int jj = 0; jj < 6; ++jj)
        P.hWiT[((size_t)g * 768 + lj6 + jj) * 1024 + k] = vv[jj];
    }
  #pragma unroll 1
  for (int g = 0; g < 3; ++g)
    for (int it = 0; it < 3; ++it) {   // high_Wh [3][768][768] -> hWhT[g][j][k]
      int k = it * 256 + tid;
      const float* src = P.hWh + ((size_t)g * 768 + k) * 768 + lj6;
      float2 a = *(const float2*)src, b2v = *(const float2*)(src + 2), c2v = *(const float2*)(src + 4);
      float vv[6] = {a.x, a.y, b2v.x, b2v.y, c2v.x, c2v.y};
      for (int jj = 0; jj < 6; ++jj)
        P.hWhT[((size_t)g * 768 + lj6 + jj) * 768 + k] = vv[jj];
    }
  #pragma unroll 1
  for (int g = 0; g < 3; ++g)
    for (int it = 0; it < 4; ++it) {   // low_Wh slice -> LDS
      int k = it * 256 + tid;
      const float* src = P.lWh + ((size_t)g * 1024 + k) * 1024 + lj8;
      float4 v0 = *(const float4*)src; float4 v1 = *(const float4*)(src + 4);
      float vv[8] = {v0.x, v0.y, v0.z, v0.w, v1.x, v1.y, v1.z, v1.w};
      for (int jj = 0; jj < 8; ++jj) WhS[(g * 8 + jj) * 1024 + k] = vv[jj];
    }
  xfun(0);
  int bt = 0;
  bt += NWG;
  bool alive = wgbar(bt);   // prologue barrier

  // =================== main recurrence ===================
  int r = 0;
  #pragma unroll 1
  for (int t = 0; alive && t < 256; ++t) {
    #pragma unroll 1
    for (int nn = 0; nn < 3; ++nn) {
      // ---- round A: xi (once per n) + inner iteration 1 ----
      ++r;
      int e = r & 1;
      {
        stats_zero_next(e);
        float accX[3][8] = {}; float accH[3][8] = {};
        stage_xcat(); __syncthreads();
        gemm_xi(accX);
        redstage(accX, 0, P.lbi, 1024, 8, lj8);
        __syncthreads();
        stage_hl(); __syncthreads();
        gemm_lowh(accH);
        redstage(accH, 1, P.lbh, 1024, 8, lj8);
        __syncthreads();
        stats_put(e, 0, 8); stats_put(e, 1, 8);
        stats_commit(e);
        alive = stats_sync(e, 0, 96); if (!alive) break;
        gate_low(true);
        bt += NWG; alive = wgbar(bt); if (!alive) break;
      }
      // ---- inner iterations 2..5 ----
      #pragma unroll 1
      for (int it = 1; it < 5; ++it) {
        ++r;
        e = r & 1;
        stats_zero_next(e);
        float acc2[3][8] = {};
        stage_hl(); __syncthreads();
        gemm_lowh(acc2);
        redstage(acc2, 1, P.lbh, 1024, 8, lj8);
        __syncthreads();
        stats_put(e, 1, 8);
        stats_commit(e);
        float pfa = 0.f;
        if (it == 3) {           // warm L2 for high-round hWiT
          for (int g = 0; g < 3; ++g)
            pf(P.hWiT + ((size_t)g * 768 + lj6) * 1024, 6144, pfa);
        } else if (it == 4) {    // warm hWhT + next round-A WiT
          for (int g = 0; g < 3; ++g)
            pf(P.hWhT + ((size_t)g * 768 + lj6) * 768, 4608, pfa);
          for (int g = 0; g < 3; ++g)
            pf(P.WiT + ((size_t)g * 1024 + lj8) * 1536, 12288, pfa);
        }
        alive = stats_sync(e, 48, 48); if (!alive) break;
        gate_low(false);
        asm volatile("" :: "v"(pfa));  // keep prefetch live
        bt += NWG; alive = wgbar(bt); if (!alive) break;
      }
      if (!alive) break;
      // ---- high GRU round ----
      ++r;
      e = r & 1;
      {
        stats_zero_next(e);
        float aX[3][8] = {}; float aH[3][8] = {};
        stage_hl(); __syncthreads();
        gemm_hxi(aX);
        redstage(aX, 0, P.hbi, 768, 6, lj6);
        __syncthreads();
        stage_hh(); __syncthreads();
        gemm_hhh(aH);
        redstage(aH, 1, P.hbh, 768, 6, lj6);
        __syncthreads();
        stats_put(e, 0, 6); stats_put(e, 1, 6);
        stats_commit(e);
        alive = stats_sync(e, 0, 96); if (!alive) break;
        gate_high(t, nn);
        if (nn == 2 && t < 255) { __syncthreads(); xfun(t + 1); }
        bt += NWG; alive = wgbar(bt); if (!alive) break;
      }
    }
  }
}

// =================== Wout transpose + bf16 convert ===================
__global__ void __launch_bounds__(256) wout_t(const float* __restrict__ W,
                                              __hip_bfloat16* __restrict__ WT) {
  __shared__ float T[64][65];
  int n0 = blockIdx.x * 64, k0 = blockIdx.y * 64;
  int tid = threadIdx.x;
  int lane16 = tid & 15, grp = tid >> 4;
  #pragma unroll
  for (int i = 0; i < 4; ++i) {
    int kl = i * 16 + grp; int nl = lane16 * 4;
    float4 v = *(const float4*)&W[(size_t)(k0 + kl) * 32000 + n0 + nl];
    T[kl][nl] = v.x; T[kl][nl + 1] = v.y; T[kl][nl + 2] = v.z; T[kl][nl + 3] = v.w;
  }
  __syncthreads();
  #pragma unroll
  for (int i = 0; i < 4; ++i) {
    int nl = i * 16 + grp; int kl = lane16 * 4;
    union { ushort4 v; __hip_bfloat16 h[4]; } u;
    for (int q = 0; q < 4; ++q) u.h[q] = __float2bfloat16(T[kl + q][nl]);
    *(ushort4*)&WT[(size_t)(n0 + nl) * 768 + k0 + kl] = u.v;
  }
}

// =================== logits GEMM: [2048,768] x [768,32000]^T-stored ===================
__global__ void __launch_bounds__(256) logits_gemm(const __hip_bfloat16* __restrict__ Ah,
                                                   const __hip_bfloat16* __restrict__ Bt,
                                                   const float* __restrict__ bias,
                                                   float* __restrict__ out) {
  __shared__ short As[128 * 64];
  __shared__ short Bs[128 * 64];
  int m0 = blockIdx.y * 128, n0 = blockIdx.x * 128;
  int tid = threadIdx.x, lane = tid & 63, w = tid >> 6;
  int wr = w >> 1, wc = w & 1;
  int r16 = lane & 15, khalf = (lane >> 4) * 8;
  f32x4 acc[4][4];
  #pragma unroll
  for (int i = 0; i < 4; ++i)
    #pragma unroll
    for (int j = 0; j < 4; ++j)
      #pragma unroll
      for (int q = 0; q < 4; ++q) acc[i][j][q] = 0.f;

  for (int kt = 0; kt < 12; ++kt) {
    int k0 = kt * 64;
    __syncthreads();
    #pragma unroll
    for (int it = 0; it < 4; ++it) {
      int f = it * 2048 + tid * 8; int row = f >> 6, col = f & 63;
      *(uint4*)&As[f] = *(const uint4*)&Ah[(size_t)(m0 + row) * 768 + k0 + col];
      *(uint4*)&Bs[f] = *(const uint4*)&Bt[(size_t)(n0 + row) * 768 + k0 + col];
    }
    __syncthreads();
    #pragma unroll
    for (int kk = 0; kk < 64; kk += 32) {
      short8 af[4], bfr[4];
      #pragma unroll
      for (int i = 0; i < 4; ++i)
        af[i] = *(short8*)&As[(wr * 64 + i * 16 + r16) * 64 + kk + khalf];
      #pragma unroll
      for (int j = 0; j < 4; ++j)
        bfr[j] = *(short8*)&Bs[(wc * 64 + j * 16 + r16) * 64 + kk + khalf];
      #pragma unroll
      for (int i = 0; i < 4; ++i)
        #pragma unroll
        for (int j = 0; j < 4; ++j)
          acc[i][j] = __builtin_amdgcn_mfma_f32_16x16x32_bf16(af[i], bfr[j], acc[i][j], 0, 0, 0);
    }
  }
  #pragma unroll
  for (int i = 0; i < 4; ++i)
    #pragma unroll
    for (int j = 0; j < 4; ++j)
      #pragma unroll
      for (int q = 0; q < 4; ++q) {
        int m = m0 + wr * 64 + i * 16 + ((lane >> 4) * 4 + q);
        int n = n0 + wc * 64 + j * 16 + (lane & 15);
        out[(size_t)(m & 7) * 8192000 + (size_t)(m >> 3) * 32000 + n] =
            acc[i][j][q] + bias[n];
      }
}

extern "C" void kernel_launch(void* const* d_in, const int* in_sizes, int n_in,
                              void* d_out, int out_size, void* d_ws, size_t ws_size,
                              hipStream_t stream) {
  (void)in_sizes; (void)n_in; (void)out_size; (void)ws_size;
  char* wsb = (char*)d_ws;
  size_t off = 0;
  auto take = [&](size_t bytes) -> void* {
    void* p = wsb + off;
    off += (bytes + 1023) & ~(size_t)1023;
    return p;
  };
  int* cnt      = (int*)take((size_t)8 * 32 * 4);          // monotonic barrier lines
  int* scnt     = (int*)take((size_t)2 * 8 * 32 * 4);      // stats arrival counters
  float* stats  = (float*)take((size_t)2 * 8 * 128 * 4);   // 2-slot x 8-replica stats
  float* hl     = (float*)take((size_t)8 * 1024 * 4);
  float* hh     = (float*)take((size_t)8 * 768 * 4);
  float* xcat   = (float*)take((size_t)8 * 1536 * 4);
  size_t state_bytes = off;   // ~120 KB
  __hip_bfloat16* hist = (__hip_bfloat16*)take((size_t)2048 * 768 * 2);
  float* WiT    = (float*)take((size_t)3 * 1024 * 1536 * 4);
  float* hWiT   = (float*)take((size_t)3 * 768 * 1024 * 4);
  float* hWhT   = (float*)take((size_t)3 * 768 * 768 * 4);
  __hip_bfloat16* WoutT = (__hip_bfloat16*)take((size_t)32000 * 768 * 2);

  hipMemsetAsync(d_ws, 0, state_bytes, stream);  // counters/stats/h-state = 0

  wout_t<<<dim3(500, 12), 256, 0, stream>>>((const float*)d_in[20], WoutT);

  PArgs A;
  A.ids = (const int*)d_in[0];   A.emb = (const float*)d_in[1];
  A.lng = (const float*)d_in[2]; A.lnb = (const float*)d_in[3];
  A.lWi = (const float*)d_in[4]; A.lbi = (const float*)d_in[5];
  A.lWh = (const float*)d_in[6]; A.lbh = (const float*)d_in[7];
  A.llig = (const float*)d_in[8];  A.llib = (const float*)d_in[9];
  A.llhg = (const float*)d_in[10]; A.llhb = (const float*)d_in[11];
  A.hWi = (const float*)d_in[12];  A.hbi = (const float*)d_in[13];
  A.hWh = (const float*)d_in[14];  A.hbh = (const float*)d_in[15];
  A.hlig = (const float*)d_in[16]; A.hlib = (const float*)d_in[17];
  A.hlhg = (const float*)d_in[18]; A.hlhb = (const float*)d_in[19];
  A.cnt = cnt; A.scnt = scnt; A.stats = stats;
  A.hl = hl; A.hh = hh; A.xcat = xcat;
  A.hist = hist; A.WiT = WiT; A.hWiT = hWiT; A.hWhT = hWhT;

  hrm_recur<<<NWG, NTH, 0, stream>>>(A);

  logits_gemm<<<dim3(250, 16), 256, 0, stream>>>(hist, WoutT,
                                                 (const float*)d_in[21],
                                                 (float*)d_out);
}